// Round 3
// baseline (723.378 us; speedup 1.0000x reference)
//
#include <hip/hip_runtime.h>

#define DIM 1024
#define NROWS 65536
#define PICK 12

// -------------------------------------------------------------------------
// ws layout (floats):
//   0      NK  [12][1024]
//   12288  Qr  [12][1024]
//   24576  M   [1024][12]   (zeroed, atomic-accumulated)
//   36864  Rt  [1024][12]   (zeroed, atomic-accumulated)
//   49152  c0  [12] (pad16, zeroed)
//   49168  c1  [12] (pad16, zeroed)
//   49184  cand_v [768]
//   49952  cand_i [768] (int)
//   50720  top_idx [12] (int, pad16)
//   50736  maxv [65536]
// -------------------------------------------------------------------------

// out[j][d] = sum_e emb[idx[j]][e] * W[d][e] + b[d]      (12 x 1024)
// grid 1024 (one block per d), block 256
__global__ void __launch_bounds__(256)
rows12_kernel(const float* __restrict__ emb, const float* __restrict__ W,
              const float* __restrict__ b, const int* __restrict__ idx,
              float* __restrict__ out) {
    int d = blockIdx.x;
    int t = threadIdx.x;
    int lane = t & 63;
    int q = t >> 6;                 // wave id: e-quarter
    int e0 = q * 256 + lane * 4;
    float4 w4 = *(const float4*)&W[(size_t)d * DIM + e0];
    float part[PICK];
#pragma unroll
    for (int j = 0; j < PICK; ++j) {
        int r = idx[j];
        float4 e4 = *(const float4*)&emb[(size_t)r * DIM + e0];
        part[j] = w4.x * e4.x + w4.y * e4.y + w4.z * e4.z + w4.w * e4.w;
    }
#pragma unroll
    for (int j = 0; j < PICK; ++j) {
        float v = part[j];
        for (int s = 32; s > 0; s >>= 1) v += __shfl_down(v, s, 64);
        part[j] = v;
    }
    __shared__ float red[4][PICK];
    if (lane == 0) {
#pragma unroll
        for (int j = 0; j < PICK; ++j) red[q][j] = part[j];
    }
    __syncthreads();
    if (t < PICK) {
        float s = red[0][t] + red[1][t] + red[2][t] + red[3][t] + b[d];
        out[t * DIM + d] = s;
    }
}

// out[e][j] += sum_d W[d][e] * V[j][d]   and  cvec[j] += sum_d b[d]*V[j][d]
// grid 129 (128 = 4 e-groups x 32 d-groups; block 128 = cvec), block 256
__global__ void __launch_bounds__(256)
colmat_kernel(const float* __restrict__ W, const float* __restrict__ V,
              const float* __restrict__ b, float* __restrict__ out,
              float* __restrict__ cvec) {
    int blk = blockIdx.x;
    int t = threadIdx.x;
    if (blk == 128) {
        float part[PICK];
#pragma unroll
        for (int j = 0; j < PICK; ++j) part[j] = 0.f;
        for (int k = 0; k < 4; ++k) {
            int d = t + k * 256;
            float bv = b[d];
#pragma unroll
            for (int j = 0; j < PICK; ++j) part[j] += bv * V[j * DIM + d];
        }
#pragma unroll
        for (int j = 0; j < PICK; ++j) {
            float v = part[j];
            for (int s = 32; s > 0; s >>= 1) v += __shfl_down(v, s, 64);
            if ((t & 63) == 0) atomicAdd(&cvec[j], v);
        }
        return;
    }
    int eg = blk & 3;
    int dg = blk >> 2;              // 0..31
    int e = eg * 256 + t;
    int d0 = dg * 32;
    __shared__ float Vs[PICK][32];
    for (int i = t; i < PICK * 32; i += 256) {   // R2 bug fix: loop, not if
        int j = i >> 5, dd = i & 31;
        Vs[j][dd] = V[j * DIM + d0 + dd];
    }
    __syncthreads();
    float acc[PICK];
#pragma unroll
    for (int j = 0; j < PICK; ++j) acc[j] = 0.f;
    for (int dd = 0; dd < 32; ++dd) {
        float w = W[(size_t)(d0 + dd) * DIM + e];
#pragma unroll
        for (int j = 0; j < PICK; ++j) acc[j] += w * Vs[j][dd];
    }
#pragma unroll
    for (int j = 0; j < PICK; ++j) atomicAdd(&out[e * PICK + j], acc[j]);
}

// pass1: block = 128 (2 waves), 64 rows/block, grid 1024.
// Wave h owns j-half [6h, 6h+6). Lane holds e = c*256 + lane*4 + x (full row
// across the wave, 16 M-rows cached in 96 VGPRs). Both waves load the same
// row (2nd hits L1). Butterfly over 6 accs; per-row half-maxes land in LDS,
// combined after all 64 rows.
__global__ void __launch_bounds__(128)
pass1_kernel(const float* __restrict__ emb, const float* __restrict__ M,
             const float* __restrict__ c0, float* __restrict__ maxv) {
    int t = threadIdx.x;
    int lane = t & 63;
    int h = t >> 6;
    float m[16][6];
#pragma unroll
    for (int c = 0; c < 4; ++c)
#pragma unroll
        for (int x = 0; x < 4; ++x) {
            const float* mp = M + (size_t)(c * 256 + lane * 4 + x) * PICK + h * 6;
#pragma unroll
            for (int jj = 0; jj < 6; ++jj) m[c * 4 + x][jj] = mp[jj];
        }
    float cb[6];
#pragma unroll
    for (int jj = 0; jj < 6; ++jj) cb[jj] = c0[h * 6 + jj];
    __shared__ float mbuf[2][64];
    const float* base = emb + (size_t)blockIdx.x * 64 * DIM + lane * 4;
    float4 cur[4];
#pragma unroll
    for (int c = 0; c < 4; ++c) cur[c] = *(const float4*)(base + c * 256);
    for (int r = 0; r < 64; ++r) {
        float4 nxt[4];
        const float* nb = base + (size_t)(r + 1 < 64 ? r + 1 : r) * DIM;
#pragma unroll
        for (int c = 0; c < 4; ++c) nxt[c] = *(const float4*)(nb + c * 256);
        float acc[6];
#pragma unroll
        for (int jj = 0; jj < 6; ++jj)
            acc[jj] = cur[0].x * m[0][jj] + cur[0].y * m[1][jj] +
                      cur[0].z * m[2][jj] + cur[0].w * m[3][jj] +
                      cur[1].x * m[4][jj] + cur[1].y * m[5][jj] +
                      cur[1].z * m[6][jj] + cur[1].w * m[7][jj] +
                      cur[2].x * m[8][jj] + cur[2].y * m[9][jj] +
                      cur[2].z * m[10][jj] + cur[2].w * m[11][jj] +
                      cur[3].x * m[12][jj] + cur[3].y * m[13][jj] +
                      cur[3].z * m[14][jj] + cur[3].w * m[15][jj];
#pragma unroll
        for (int s = 1; s < 64; s <<= 1)
#pragma unroll
            for (int jj = 0; jj < 6; ++jj) acc[jj] += __shfl_xor(acc[jj], s, 64);
        float mx = acc[0] + cb[0];
#pragma unroll
        for (int jj = 1; jj < 6; ++jj) mx = fmaxf(mx, acc[jj] + cb[jj]);
        if (lane == 0) mbuf[h][r] = mx;
#pragma unroll
        for (int c = 0; c < 4; ++c) cur[c] = nxt[c];
    }
    __syncthreads();
    if (t < 64) maxv[blockIdx.x * 64 + t] = fmaxf(mbuf[0][t], mbuf[1][t]);
}

// pass2: same structure; per-row the two half-maxes are exchanged through a
// parity-double-buffered 2-float LDS slot (1 barrier/row); every lane then
// holds the row's pooled value and reuses its in-register row segment for
// out += pooled * emb[row] — zero extra HBM. Wave h accumulates the disjoint
// e-half [512h, 512h+512); 8 atomicAdds/lane once at block end.
__global__ void __launch_bounds__(128)
pass2_kernel(const float* __restrict__ emb, const float* __restrict__ Rt,
             const float* __restrict__ c1, float* __restrict__ out) {
    int t = threadIdx.x;
    int lane = t & 63;
    int h = t >> 6;
    float m[16][6];
#pragma unroll
    for (int c = 0; c < 4; ++c)
#pragma unroll
        for (int x = 0; x < 4; ++x) {
            const float* mp = Rt + (size_t)(c * 256 + lane * 4 + x) * PICK + h * 6;
#pragma unroll
            for (int jj = 0; jj < 6; ++jj) m[c * 4 + x][jj] = mp[jj];
        }
    float cb[6];
#pragma unroll
    for (int jj = 0; jj < 6; ++jj) cb[jj] = c1[h * 6 + jj];
    __shared__ float xbuf[2][2];
    const float* base = emb + (size_t)blockIdx.x * 64 * DIM + lane * 4;
    float4 cur[4];
#pragma unroll
    for (int c = 0; c < 4; ++c) cur[c] = *(const float4*)(base + c * 256);
    float o[2][4];
#pragma unroll
    for (int ci = 0; ci < 2; ++ci)
#pragma unroll
        for (int x = 0; x < 4; ++x) o[ci][x] = 0.f;
    for (int r = 0; r < 64; ++r) {
        float4 nxt[4];
        const float* nb = base + (size_t)(r + 1 < 64 ? r + 1 : r) * DIM;
#pragma unroll
        for (int c = 0; c < 4; ++c) nxt[c] = *(const float4*)(nb + c * 256);
        float acc[6];
#pragma unroll
        for (int jj = 0; jj < 6; ++jj)
            acc[jj] = cur[0].x * m[0][jj] + cur[0].y * m[1][jj] +
                      cur[0].z * m[2][jj] + cur[0].w * m[3][jj] +
                      cur[1].x * m[4][jj] + cur[1].y * m[5][jj] +
                      cur[1].z * m[6][jj] + cur[1].w * m[7][jj] +
                      cur[2].x * m[8][jj] + cur[2].y * m[9][jj] +
                      cur[2].z * m[10][jj] + cur[2].w * m[11][jj] +
                      cur[3].x * m[12][jj] + cur[3].y * m[13][jj] +
                      cur[3].z * m[14][jj] + cur[3].w * m[15][jj];
#pragma unroll
        for (int s = 1; s < 64; s <<= 1)
#pragma unroll
            for (int jj = 0; jj < 6; ++jj) acc[jj] += __shfl_xor(acc[jj], s, 64);
        float mxh = acc[0] + cb[0];
#pragma unroll
        for (int jj = 1; jj < 6; ++jj) mxh = fmaxf(mxh, acc[jj] + cb[jj]);
        int p = r & 1;
        if (lane == 0) xbuf[p][h] = mxh;
        __syncthreads();
        float mx = fmaxf(xbuf[p][0], xbuf[p][1]);
#pragma unroll
        for (int ci = 0; ci < 2; ++ci) {
            float4 v = cur[2 * h + ci];
            o[ci][0] += mx * v.x; o[ci][1] += mx * v.y;
            o[ci][2] += mx * v.z; o[ci][3] += mx * v.w;
        }
#pragma unroll
        for (int c = 0; c < 4; ++c) cur[c] = nxt[c];
    }
#pragma unroll
    for (int ci = 0; ci < 2; ++ci)
#pragma unroll
        for (int x = 0; x < 4; ++x)
            atomicAdd(&out[(2 * h + ci) * 256 + lane * 4 + x], o[ci][x]);
}

// local top-12 of each 1024-chunk of maxv -> 64 blocks x 12 candidates
__global__ void __launch_bounds__(256)
top12_local(const float* __restrict__ maxv, float* __restrict__ cand_v,
            int* __restrict__ cand_i) {
    int t = threadIdx.x;
    int base = blockIdx.x * 1024;
    __shared__ float mv[1024];
    __shared__ float sv[256];
    __shared__ int si[256];
    for (int i = t; i < 1024; i += 256) mv[i] = maxv[base + i];
    __syncthreads();
    for (int k = 0; k < PICK; ++k) {
        float bv = -3e38f; int bi = 0x7fffffff;
        for (int i = t; i < 1024; i += 256) {
            float v = mv[i];
            if (v > bv || (v == bv && base + i < bi)) { bv = v; bi = base + i; }
        }
        sv[t] = bv; si[t] = bi;
        __syncthreads();
        for (int s = 128; s > 0; s >>= 1) {
            if (t < s) {
                if (sv[t + s] > sv[t] || (sv[t + s] == sv[t] && si[t + s] < si[t])) {
                    sv[t] = sv[t + s]; si[t] = si[t + s];
                }
            }
            __syncthreads();
        }
        if (t == 0) {
            cand_v[blockIdx.x * PICK + k] = sv[0];
            cand_i[blockIdx.x * PICK + k] = si[0];
            mv[si[0] - base] = -3e38f;
        }
        __syncthreads();
    }
}

// merge 768 candidates -> global top-12 indices
__global__ void __launch_bounds__(256)
top12_merge(const float* __restrict__ cand_v, const int* __restrict__ cand_i,
            int* __restrict__ top_idx) {
    int t = threadIdx.x;
    __shared__ float mv[768];
    __shared__ int mi[768];
    __shared__ float sv[256];
    __shared__ int si[256];
    __shared__ int sl[256];
    for (int i = t; i < 768; i += 256) { mv[i] = cand_v[i]; mi[i] = cand_i[i]; }
    __syncthreads();
    for (int k = 0; k < PICK; ++k) {
        float bv = -3e38f; int bi = 0x7fffffff; int bl = -1;
        for (int i = t; i < 768; i += 256) {
            float v = mv[i]; int ii = mi[i];
            if (v > bv || (v == bv && ii < bi)) { bv = v; bi = ii; bl = i; }
        }
        sv[t] = bv; si[t] = bi; sl[t] = bl;
        __syncthreads();
        for (int s = 128; s > 0; s >>= 1) {
            if (t < s) {
                if (sv[t + s] > sv[t] || (sv[t + s] == sv[t] && si[t + s] < si[t])) {
                    sv[t] = sv[t + s]; si[t] = si[t + s]; sl[t] = sl[t + s];
                }
            }
            __syncthreads();
        }
        if (t == 0) { top_idx[k] = si[0]; mv[sl[0]] = -3e38f; }
        __syncthreads();
    }
}

extern "C" void kernel_launch(void* const* d_in, const int* in_sizes, int n_in,
                              void* d_out, int out_size, void* d_ws, size_t ws_size,
                              hipStream_t stream) {
    const float* emb = (const float*)d_in[0];
    const float* Wq  = (const float*)d_in[1];
    const float* bq  = (const float*)d_in[2];
    const float* Wk  = (const float*)d_in[3];
    const float* bk  = (const float*)d_in[4];
    const int* indices = (const int*)d_in[5];
    float* out = (float*)d_out;
    float* ws = (float*)d_ws;

    float* NK      = ws;             // 12288
    float* Qr      = ws + 12288;     // 12288
    float* M       = ws + 24576;     // 12288 (zeroed)
    float* Rt      = ws + 36864;     // 12288 (zeroed)
    float* c0      = ws + 49152;     // 16    (zeroed)
    float* c1      = ws + 49168;     // 16    (zeroed)
    float* cand_v  = ws + 49184;     // 768
    int*   cand_i  = (int*)(ws + 49952);   // 768
    int*   top_idx = (int*)(ws + 50720);   // 16
    float* maxv    = ws + 50736;     // 65536

    // zero the atomic-accumulated regions (M, Rt, c0, c1) and the output
    hipMemsetAsync(M, 0, (size_t)(12288 * 2 + 32) * sizeof(float), stream);
    hipMemsetAsync(out, 0, DIM * sizeof(float), stream);

    rows12_kernel<<<1024, 256, 0, stream>>>(emb, Wk, bk, indices, NK);
    colmat_kernel<<<129, 256, 0, stream>>>(Wq, NK, bq, M, c0);
    pass1_kernel<<<1024, 128, 0, stream>>>(emb, M, c0, maxv);
    top12_local<<<64, 256, 0, stream>>>(maxv, cand_v, cand_i);
    top12_merge<<<1, 256, 0, stream>>>(cand_v, cand_i, top_idx);
    rows12_kernel<<<1024, 256, 0, stream>>>(emb, Wq, bq, top_idx, Qr);
    colmat_kernel<<<129, 256, 0, stream>>>(Wk, Qr, bk, Rt, c1);
    pass2_kernel<<<1024, 128, 0, stream>>>(emb, Rt, c1, out);
}

// Round 4
// 606.783 us; speedup vs baseline: 1.1922x; 1.1922x over previous
//
#include <hip/hip_runtime.h>

#define DIM 1024
#define NROWS 65536
#define PICK 12

// -------------------------------------------------------------------------
// ws layout (floats):
//   0      NK  [12][1024]
//   12288  Qr  [12][1024]
//   24576  M   [1024][12]   (zeroed, atomic-accumulated)
//   36864  Rt  [1024][12]   (zeroed, atomic-accumulated)
//   49152  c0  [12] (pad16, zeroed)
//   49168  c1  [12] (pad16, zeroed)
//   49184  cand_v [768]
//   49952  cand_i [768] (int)
//   50720  top_idx [12] (int, pad16)
//   50736  maxv [65536]
// -------------------------------------------------------------------------

// out[j][d] = sum_e emb[idx[j]][e] * W[d][e] + b[d]      (12 x 1024)
__global__ void __launch_bounds__(256)
rows12_kernel(const float* __restrict__ emb, const float* __restrict__ W,
              const float* __restrict__ b, const int* __restrict__ idx,
              float* __restrict__ out) {
    int d = blockIdx.x;
    int t = threadIdx.x;
    int lane = t & 63;
    int q = t >> 6;
    int e0 = q * 256 + lane * 4;
    float4 w4 = *(const float4*)&W[(size_t)d * DIM + e0];
    float part[PICK];
#pragma unroll
    for (int j = 0; j < PICK; ++j) {
        int r = idx[j];
        float4 e4 = *(const float4*)&emb[(size_t)r * DIM + e0];
        part[j] = w4.x * e4.x + w4.y * e4.y + w4.z * e4.z + w4.w * e4.w;
    }
#pragma unroll
    for (int j = 0; j < PICK; ++j) {
        float v = part[j];
        for (int s = 32; s > 0; s >>= 1) v += __shfl_down(v, s, 64);
        part[j] = v;
    }
    __shared__ float red[4][PICK];
    if (lane == 0) {
#pragma unroll
        for (int j = 0; j < PICK; ++j) red[q][j] = part[j];
    }
    __syncthreads();
    if (t < PICK) {
        float s = red[0][t] + red[1][t] + red[2][t] + red[3][t] + b[d];
        out[t * DIM + d] = s;
    }
}

// out[e][j] += sum_d W[d][e] * V[j][d]   and  cvec[j] += sum_d b[d]*V[j][d]
__global__ void __launch_bounds__(256)
colmat_kernel(const float* __restrict__ W, const float* __restrict__ V,
              const float* __restrict__ b, float* __restrict__ out,
              float* __restrict__ cvec) {
    int blk = blockIdx.x;
    int t = threadIdx.x;
    if (blk == 128) {
        float part[PICK];
#pragma unroll
        for (int j = 0; j < PICK; ++j) part[j] = 0.f;
        for (int k = 0; k < 4; ++k) {
            int d = t + k * 256;
            float bv = b[d];
#pragma unroll
            for (int j = 0; j < PICK; ++j) part[j] += bv * V[j * DIM + d];
        }
#pragma unroll
        for (int j = 0; j < PICK; ++j) {
            float v = part[j];
            for (int s = 32; s > 0; s >>= 1) v += __shfl_down(v, s, 64);
            if ((t & 63) == 0) atomicAdd(&cvec[j], v);
        }
        return;
    }
    int eg = blk & 3;
    int dg = blk >> 2;
    int e = eg * 256 + t;
    int d0 = dg * 32;
    __shared__ float Vs[PICK][32];
    for (int i = t; i < PICK * 32; i += 256) {
        int j = i >> 5, dd = i & 31;
        Vs[j][dd] = V[j * DIM + d0 + dd];
    }
    __syncthreads();
    float acc[PICK];
#pragma unroll
    for (int j = 0; j < PICK; ++j) acc[j] = 0.f;
    for (int dd = 0; dd < 32; ++dd) {
        float w = W[(size_t)(d0 + dd) * DIM + e];
#pragma unroll
        for (int j = 0; j < PICK; ++j) acc[j] += w * Vs[j][dd];
    }
#pragma unroll
    for (int j = 0; j < PICK; ++j) atomicAdd(&out[e * PICK + j], acc[j]);
}

// Shared phase-A helper pattern (pass1/pass2):
// block 512 = 8 waves; wave = 16 row-groups of 4 lanes (g=l>>2, s=l&3).
// Lane walks cols c = i*16 + s*4 (i=0..63): each wave-load = 16 full 64B
// lines. acc[12] accumulates privately over the whole row; ONE 2-stage
// 4-lane butterfly at the end (24 shuffles / 16 rows). M in LDS; the 12
// ds_read_b128/iter have 4 distinct addrs on disjoint bank pairs (2-way =
// free) with 16-way broadcast.

__global__ void __launch_bounds__(512)
pass1_kernel(const float* __restrict__ emb, const float* __restrict__ M,
             const float* __restrict__ c0, float* __restrict__ maxv) {
    __shared__ float sM[DIM * PICK];          // 48 KB
    int t = threadIdx.x;
    for (int i = t; i < DIM * PICK / 4; i += 512)
        ((float4*)sM)[i] = ((const float4*)M)[i];
    __syncthreads();

    int l = t & 63, w = t >> 6;
    int g = l >> 2, s = l & 3;
    size_t row = (size_t)blockIdx.x * 128 + w * 16 + g;
    const float* rp = emb + row * DIM + s * 4;
    float cb[PICK];
#pragma unroll
    for (int j = 0; j < PICK; ++j) cb[j] = c0[j];

    float acc[PICK];
#pragma unroll
    for (int j = 0; j < PICK; ++j) acc[j] = 0.f;
    float4 cur = *(const float4*)rp;
#pragma unroll 4
    for (int i = 0; i < 64; ++i) {
        float4 nxt = *(const float4*)(rp + (i + 1 < 64 ? i + 1 : i) * 16);
        const float* mb = sM + (size_t)(i * 16 + s * 4) * PICK;
        float f[4] = {cur.x, cur.y, cur.z, cur.w};
#pragma unroll
        for (int x = 0; x < 4; ++x) {
            float4 m0 = *(const float4*)(mb + x * PICK + 0);
            float4 m1 = *(const float4*)(mb + x * PICK + 4);
            float4 m2 = *(const float4*)(mb + x * PICK + 8);
            acc[0] += f[x] * m0.x; acc[1] += f[x] * m0.y;
            acc[2] += f[x] * m0.z; acc[3] += f[x] * m0.w;
            acc[4] += f[x] * m1.x; acc[5] += f[x] * m1.y;
            acc[6] += f[x] * m1.z; acc[7] += f[x] * m1.w;
            acc[8] += f[x] * m2.x; acc[9] += f[x] * m2.y;
            acc[10] += f[x] * m2.z; acc[11] += f[x] * m2.w;
        }
        cur = nxt;
    }
    // one 4-lane butterfly for the whole row
#pragma unroll
    for (int j = 0; j < PICK; ++j) {
        acc[j] += __shfl_xor(acc[j], 1, 64);
        acc[j] += __shfl_xor(acc[j], 2, 64);
    }
    float mx = acc[0] + cb[0];
#pragma unroll
    for (int j = 1; j < PICK; ++j) mx = fmaxf(mx, acc[j] + cb[j]);
    if (s == 0) maxv[row] = mx;
}

__global__ void __launch_bounds__(512)
pass2_kernel(const float* __restrict__ emb, const float* __restrict__ Rt,
             const float* __restrict__ c1, float* __restrict__ out) {
    __shared__ float sM[DIM * PICK];          // 48 KB
    __shared__ float pooled[8][16];           // 512 B
    __shared__ float obuf[2][DIM];            // 8 KB   (total 57.8 KB)
    int t = threadIdx.x;
    for (int i = t; i < DIM * PICK / 4; i += 512)
        ((float4*)sM)[i] = ((const float4*)Rt)[i];
    __syncthreads();

    int l = t & 63, w = t >> 6;
    int g = l >> 2, s = l & 3;
    size_t rbase = (size_t)blockIdx.x * 128 + w * 16;
    size_t row = rbase + g;
    const float* rp = emb + row * DIM + s * 4;
    float cb[PICK];
#pragma unroll
    for (int j = 0; j < PICK; ++j) cb[j] = c1[j];

    float acc[PICK];
#pragma unroll
    for (int j = 0; j < PICK; ++j) acc[j] = 0.f;
    float4 cur = *(const float4*)rp;
#pragma unroll 4
    for (int i = 0; i < 64; ++i) {
        float4 nxt = *(const float4*)(rp + (i + 1 < 64 ? i + 1 : i) * 16);
        const float* mb = sM + (size_t)(i * 16 + s * 4) * PICK;
        float f[4] = {cur.x, cur.y, cur.z, cur.w};
#pragma unroll
        for (int x = 0; x < 4; ++x) {
            float4 m0 = *(const float4*)(mb + x * PICK + 0);
            float4 m1 = *(const float4*)(mb + x * PICK + 4);
            float4 m2 = *(const float4*)(mb + x * PICK + 8);
            acc[0] += f[x] * m0.x; acc[1] += f[x] * m0.y;
            acc[2] += f[x] * m0.z; acc[3] += f[x] * m0.w;
            acc[4] += f[x] * m1.x; acc[5] += f[x] * m1.y;
            acc[6] += f[x] * m1.z; acc[7] += f[x] * m1.w;
            acc[8] += f[x] * m2.x; acc[9] += f[x] * m2.y;
            acc[10] += f[x] * m2.z; acc[11] += f[x] * m2.w;
        }
        cur = nxt;
    }
#pragma unroll
    for (int j = 0; j < PICK; ++j) {
        acc[j] += __shfl_xor(acc[j], 1, 64);
        acc[j] += __shfl_xor(acc[j], 2, 64);
    }
    float mx = acc[0] + cb[0];
#pragma unroll
    for (int j = 1; j < PICK; ++j) mx = fmaxf(mx, acc[j] + cb[j]);
    // wave-local exchange: same-wave LDS store->load is ordered, no barrier
    if (s == 0) pooled[w][g] = mx;

    // phase B: wave re-walks its own 16 rows (L2/L3-hot), fixed col ownership
    float o[4][4];
#pragma unroll
    for (int c = 0; c < 4; ++c)
#pragma unroll
        for (int x = 0; x < 4; ++x) o[c][x] = 0.f;
    const float* tp = emb + rbase * DIM + l * 4;
    for (int r = 0; r < 16; ++r) {
        float p = pooled[w][r];
#pragma unroll
        for (int c = 0; c < 4; ++c) {
            float4 v = *(const float4*)(tp + (size_t)r * DIM + c * 256);
            o[c][0] += p * v.x; o[c][1] += p * v.y;
            o[c][2] += p * v.z; o[c][3] += p * v.w;
        }
    }
    // stage per wave-pair into obuf[2][1024], 4 phases
    for (int ph = 0; ph < 4; ++ph) {
        if ((w >> 1) == ph) {
            float* ob = obuf[w & 1];
            if (ph == 0) {
#pragma unroll
                for (int c = 0; c < 4; ++c)
                    *(float4*)(ob + c * 256 + l * 4) = *(float4*)o[c];
            } else {
#pragma unroll
                for (int c = 0; c < 4; ++c) {
                    float4 prev = *(float4*)(ob + c * 256 + l * 4);
                    prev.x += o[c][0]; prev.y += o[c][1];
                    prev.z += o[c][2]; prev.w += o[c][3];
                    *(float4*)(ob + c * 256 + l * 4) = prev;
                }
            }
        }
        __syncthreads();
    }
    for (int c = t; c < DIM; c += 512)
        atomicAdd(&out[c], obuf[0][c] + obuf[1][c]);
}

// local top-12 of each 1024-chunk of maxv -> 64 blocks x 12 candidates
__global__ void __launch_bounds__(256)
top12_local(const float* __restrict__ maxv, float* __restrict__ cand_v,
            int* __restrict__ cand_i) {
    int t = threadIdx.x;
    int base = blockIdx.x * 1024;
    __shared__ float mv[1024];
    __shared__ float sv[256];
    __shared__ int si[256];
    for (int i = t; i < 1024; i += 256) mv[i] = maxv[base + i];
    __syncthreads();
    for (int k = 0; k < PICK; ++k) {
        float bv = -3e38f; int bi = 0x7fffffff;
        for (int i = t; i < 1024; i += 256) {
            float v = mv[i];
            if (v > bv || (v == bv && base + i < bi)) { bv = v; bi = base + i; }
        }
        sv[t] = bv; si[t] = bi;
        __syncthreads();
        for (int s = 128; s > 0; s >>= 1) {
            if (t < s) {
                if (sv[t + s] > sv[t] || (sv[t + s] == sv[t] && si[t + s] < si[t])) {
                    sv[t] = sv[t + s]; si[t] = si[t + s];
                }
            }
            __syncthreads();
        }
        if (t == 0) {
            cand_v[blockIdx.x * PICK + k] = sv[0];
            cand_i[blockIdx.x * PICK + k] = si[0];
            mv[si[0] - base] = -3e38f;
        }
        __syncthreads();
    }
}

// merge 768 candidates -> global top-12 indices
__global__ void __launch_bounds__(256)
top12_merge(const float* __restrict__ cand_v, const int* __restrict__ cand_i,
            int* __restrict__ top_idx) {
    int t = threadIdx.x;
    __shared__ float mv[768];
    __shared__ int mi[768];
    __shared__ float sv[256];
    __shared__ int si[256];
    __shared__ int sl[256];
    for (int i = t; i < 768; i += 256) { mv[i] = cand_v[i]; mi[i] = cand_i[i]; }
    __syncthreads();
    for (int k = 0; k < PICK; ++k) {
        float bv = -3e38f; int bi = 0x7fffffff; int bl = -1;
        for (int i = t; i < 768; i += 256) {
            float v = mv[i]; int ii = mi[i];
            if (v > bv || (v == bv && ii < bi)) { bv = v; bi = ii; bl = i; }
        }
        sv[t] = bv; si[t] = bi; sl[t] = bl;
        __syncthreads();
        for (int s = 128; s > 0; s >>= 1) {
            if (t < s) {
                if (sv[t + s] > sv[t] || (sv[t + s] == sv[t] && si[t + s] < si[t])) {
                    sv[t] = sv[t + s]; si[t] = si[t + s]; sl[t] = sl[t + s];
                }
            }
            __syncthreads();
        }
        if (t == 0) { top_idx[k] = si[0]; mv[sl[0]] = -3e38f; }
        __syncthreads();
    }
}

extern "C" void kernel_launch(void* const* d_in, const int* in_sizes, int n_in,
                              void* d_out, int out_size, void* d_ws, size_t ws_size,
                              hipStream_t stream) {
    const float* emb = (const float*)d_in[0];
    const float* Wq  = (const float*)d_in[1];
    const float* bq  = (const float*)d_in[2];
    const float* Wk  = (const float*)d_in[3];
    const float* bk  = (const float*)d_in[4];
    const int* indices = (const int*)d_in[5];
    float* out = (float*)d_out;
    float* ws = (float*)d_ws;

    float* NK      = ws;             // 12288
    float* Qr      = ws + 12288;     // 12288
    float* M       = ws + 24576;     // 12288 (zeroed)
    float* Rt      = ws + 36864;     // 12288 (zeroed)
    float* c0      = ws + 49152;     // 16    (zeroed)
    float* c1      = ws + 49168;     // 16    (zeroed)
    float* cand_v  = ws + 49184;     // 768
    int*   cand_i  = (int*)(ws + 49952);   // 768
    int*   top_idx = (int*)(ws + 50720);   // 16
    float* maxv    = ws + 50736;     // 65536

    hipMemsetAsync(M, 0, (size_t)(12288 * 2 + 32) * sizeof(float), stream);
    hipMemsetAsync(out, 0, DIM * sizeof(float), stream);

    rows12_kernel<<<1024, 256, 0, stream>>>(emb, Wk, bk, indices, NK);
    colmat_kernel<<<129, 256, 0, stream>>>(Wq, NK, bq, M, c0);
    pass1_kernel<<<512, 512, 0, stream>>>(emb, M, c0, maxv);
    top12_local<<<64, 256, 0, stream>>>(maxv, cand_v, cand_i);
    top12_merge<<<1, 256, 0, stream>>>(cand_v, cand_i, top_idx);
    rows12_kernel<<<1024, 256, 0, stream>>>(emb, Wq, bq, top_idx, Qr);
    colmat_kernel<<<129, 256, 0, stream>>>(Wk, Qr, bk, Rt, c1);
    pass2_kernel<<<512, 512, 0, stream>>>(emb, Rt, c1, out);
}

// Round 5
// 594.705 us; speedup vs baseline: 1.2164x; 1.0203x over previous
//
#include <hip/hip_runtime.h>

#define DIM 1024
#define NROWS 65536
#define PICK 12

// -------------------------------------------------------------------------
// ws layout (floats):
//   0      NK  [12][1024]
//   12288  Qr  [12][1024]
//   24576  M   [1024][12]   (zeroed, atomic-accumulated)
//   36864  Rt  [1024][12]   (zeroed, atomic-accumulated)
//   49152  c0  [12] (pad16, zeroed)
//   49168  c1  [12] (pad16, zeroed)
//   49184  cand_v [768]
//   49952  cand_i [768] (int)
//   50720  top_idx [12] (int, pad16)
//   50736  maxv [65536]
// -------------------------------------------------------------------------

// out[j][d] = sum_e emb[idx[j]][e] * W[d][e] + b[d]      (12 x 1024)
__global__ void __launch_bounds__(256)
rows12_kernel(const float* __restrict__ emb, const float* __restrict__ W,
              const float* __restrict__ b, const int* __restrict__ idx,
              float* __restrict__ out) {
    int d = blockIdx.x;
    int t = threadIdx.x;
    int lane = t & 63;
    int q = t >> 6;
    int e0 = q * 256 + lane * 4;
    float4 w4 = *(const float4*)&W[(size_t)d * DIM + e0];
    float part[PICK];
#pragma unroll
    for (int j = 0; j < PICK; ++j) {
        int r = idx[j];
        float4 e4 = *(const float4*)&emb[(size_t)r * DIM + e0];
        part[j] = w4.x * e4.x + w4.y * e4.y + w4.z * e4.z + w4.w * e4.w;
    }
#pragma unroll
    for (int j = 0; j < PICK; ++j) {
        float v = part[j];
        for (int s = 32; s > 0; s >>= 1) v += __shfl_down(v, s, 64);
        part[j] = v;
    }
    __shared__ float red[4][PICK];
    if (lane == 0) {
#pragma unroll
        for (int j = 0; j < PICK; ++j) red[q][j] = part[j];
    }
    __syncthreads();
    if (t < PICK) {
        float s = red[0][t] + red[1][t] + red[2][t] + red[3][t] + b[d];
        out[t * DIM + d] = s;
    }
}

// out[e][j] += sum_d W[d][e] * V[j][d]   and  cvec[j] += sum_d b[d]*V[j][d]
__global__ void __launch_bounds__(256)
colmat_kernel(const float* __restrict__ W, const float* __restrict__ V,
              const float* __restrict__ b, float* __restrict__ out,
              float* __restrict__ cvec) {
    int blk = blockIdx.x;
    int t = threadIdx.x;
    if (blk == 128) {
        float part[PICK];
#pragma unroll
        for (int j = 0; j < PICK; ++j) part[j] = 0.f;
        for (int k = 0; k < 4; ++k) {
            int d = t + k * 256;
            float bv = b[d];
#pragma unroll
            for (int j = 0; j < PICK; ++j) part[j] += bv * V[j * DIM + d];
        }
#pragma unroll
        for (int j = 0; j < PICK; ++j) {
            float v = part[j];
            for (int s = 32; s > 0; s >>= 1) v += __shfl_down(v, s, 64);
            if ((t & 63) == 0) atomicAdd(&cvec[j], v);
        }
        return;
    }
    int eg = blk & 3;
    int dg = blk >> 2;
    int e = eg * 256 + t;
    int d0 = dg * 32;
    __shared__ float Vs[PICK][32];
    for (int i = t; i < PICK * 32; i += 256) {
        int j = i >> 5, dd = i & 31;
        Vs[j][dd] = V[j * DIM + d0 + dd];
    }
    __syncthreads();
    float acc[PICK];
#pragma unroll
    for (int j = 0; j < PICK; ++j) acc[j] = 0.f;
    for (int dd = 0; dd < 32; ++dd) {
        float w = W[(size_t)(d0 + dd) * DIM + e];
#pragma unroll
        for (int j = 0; j < PICK; ++j) acc[j] += w * Vs[j][dd];
    }
#pragma unroll
    for (int j = 0; j < PICK; ++j) atomicAdd(&out[e * PICK + j], acc[j]);
}

// pass structure: block 256 (4 waves), 256 rows/block, grid 256.
// Wave = 16 groups of 4 lanes (g=l>>2, s=l&3); group g owns rows
// {rr*16+g, rr=0..3} of its wave's 64. Lane walks cols i*16+s*4 (i=0..63).
// The M chunk (48 floats, 12 ds_read_b128) is read ONCE per iter and applied
// to all 4 rows -> 12 LDS instrs/row (vs 48 in R4) — under the HBM budget.
// One 2-stage 4-lane butterfly per 4 rows at the end.

__global__ void __launch_bounds__(256)
pass1_kernel(const float* __restrict__ emb, const float* __restrict__ M,
             const float* __restrict__ c0, float* __restrict__ maxv) {
    __shared__ float sM[DIM * PICK];          // 48 KB
    int t = threadIdx.x;
    for (int i = t; i < DIM * PICK / 4; i += 256)
        ((float4*)sM)[i] = ((const float4*)M)[i];
    __syncthreads();

    int l = t & 63, w = t >> 6;
    int g = l >> 2, s = l & 3;
    size_t wbase = (size_t)blockIdx.x * 256 + w * 64;
    const float* rp[4];
    float4 cur[4];
#pragma unroll
    for (int rr = 0; rr < 4; ++rr) {
        rp[rr] = emb + (wbase + rr * 16 + g) * DIM + s * 4;
        cur[rr] = *(const float4*)rp[rr];
    }
    float cb[PICK];
#pragma unroll
    for (int j = 0; j < PICK; ++j) cb[j] = c0[j];

    float acc[4][PICK];
#pragma unroll
    for (int rr = 0; rr < 4; ++rr)
#pragma unroll
        for (int j = 0; j < PICK; ++j) acc[rr][j] = 0.f;

    for (int i = 0; i < 64; ++i) {
        int ip = (i + 1 < 64) ? i + 1 : i;
        float4 nxt[4];
#pragma unroll
        for (int rr = 0; rr < 4; ++rr) nxt[rr] = *(const float4*)(rp[rr] + ip * 16);
        const float* mb = sM + (size_t)(i * 16 + s * 4) * PICK;
        float4 m[12];
#pragma unroll
        for (int k = 0; k < 12; ++k) m[k] = *(const float4*)(mb + k * 4);
#pragma unroll
        for (int rr = 0; rr < 4; ++rr) {
            float f[4] = {cur[rr].x, cur[rr].y, cur[rr].z, cur[rr].w};
#pragma unroll
            for (int x = 0; x < 4; ++x) {
                float4 a0 = m[3 * x], a1 = m[3 * x + 1], a2 = m[3 * x + 2];
                acc[rr][0] += f[x] * a0.x; acc[rr][1] += f[x] * a0.y;
                acc[rr][2] += f[x] * a0.z; acc[rr][3] += f[x] * a0.w;
                acc[rr][4] += f[x] * a1.x; acc[rr][5] += f[x] * a1.y;
                acc[rr][6] += f[x] * a1.z; acc[rr][7] += f[x] * a1.w;
                acc[rr][8] += f[x] * a2.x; acc[rr][9] += f[x] * a2.y;
                acc[rr][10] += f[x] * a2.z; acc[rr][11] += f[x] * a2.w;
            }
        }
#pragma unroll
        for (int rr = 0; rr < 4; ++rr) cur[rr] = nxt[rr];
    }
#pragma unroll
    for (int rr = 0; rr < 4; ++rr)
#pragma unroll
        for (int j = 0; j < PICK; ++j) {
            acc[rr][j] += __shfl_xor(acc[rr][j], 1, 64);
            acc[rr][j] += __shfl_xor(acc[rr][j], 2, 64);
        }
    float mx[4];
#pragma unroll
    for (int rr = 0; rr < 4; ++rr) {
        float v = acc[rr][0] + cb[0];
#pragma unroll
        for (int j = 1; j < PICK; ++j) v = fmaxf(v, acc[rr][j] + cb[j]);
        mx[rr] = v;
    }
    float sel = (s == 0) ? mx[0] : (s == 1) ? mx[1] : (s == 2) ? mx[2] : mx[3];
    maxv[wbase + s * 16 + g] = sel;
}

__global__ void __launch_bounds__(256)
pass2_kernel(const float* __restrict__ emb, const float* __restrict__ Rt,
             const float* __restrict__ c1, float* __restrict__ out) {
    __shared__ float sM[DIM * PICK];          // 48 KB
    __shared__ float pooled[256];             // 1 KB
    int t = threadIdx.x;
    for (int i = t; i < DIM * PICK / 4; i += 256)
        ((float4*)sM)[i] = ((const float4*)Rt)[i];
    __syncthreads();

    int l = t & 63, w = t >> 6;
    int g = l >> 2, s = l & 3;
    size_t bbase = (size_t)blockIdx.x * 256;
    size_t wbase = bbase + w * 64;
    const float* rp[4];
    float4 cur[4];
#pragma unroll
    for (int rr = 0; rr < 4; ++rr) {
        rp[rr] = emb + (wbase + rr * 16 + g) * DIM + s * 4;
        cur[rr] = *(const float4*)rp[rr];
    }
    float cb[PICK];
#pragma unroll
    for (int j = 0; j < PICK; ++j) cb[j] = c1[j];

    float acc[4][PICK];
#pragma unroll
    for (int rr = 0; rr < 4; ++rr)
#pragma unroll
        for (int j = 0; j < PICK; ++j) acc[rr][j] = 0.f;

    for (int i = 0; i < 64; ++i) {
        int ip = (i + 1 < 64) ? i + 1 : i;
        float4 nxt[4];
#pragma unroll
        for (int rr = 0; rr < 4; ++rr) nxt[rr] = *(const float4*)(rp[rr] + ip * 16);
        const float* mb = sM + (size_t)(i * 16 + s * 4) * PICK;
        float4 m[12];
#pragma unroll
        for (int k = 0; k < 12; ++k) m[k] = *(const float4*)(mb + k * 4);
#pragma unroll
        for (int rr = 0; rr < 4; ++rr) {
            float f[4] = {cur[rr].x, cur[rr].y, cur[rr].z, cur[rr].w};
#pragma unroll
            for (int x = 0; x < 4; ++x) {
                float4 a0 = m[3 * x], a1 = m[3 * x + 1], a2 = m[3 * x + 2];
                acc[rr][0] += f[x] * a0.x; acc[rr][1] += f[x] * a0.y;
                acc[rr][2] += f[x] * a0.z; acc[rr][3] += f[x] * a0.w;
                acc[rr][4] += f[x] * a1.x; acc[rr][5] += f[x] * a1.y;
                acc[rr][6] += f[x] * a1.z; acc[rr][7] += f[x] * a1.w;
                acc[rr][8] += f[x] * a2.x; acc[rr][9] += f[x] * a2.y;
                acc[rr][10] += f[x] * a2.z; acc[rr][11] += f[x] * a2.w;
            }
        }
#pragma unroll
        for (int rr = 0; rr < 4; ++rr) cur[rr] = nxt[rr];
    }
#pragma unroll
    for (int rr = 0; rr < 4; ++rr)
#pragma unroll
        for (int j = 0; j < PICK; ++j) {
            acc[rr][j] += __shfl_xor(acc[rr][j], 1, 64);
            acc[rr][j] += __shfl_xor(acc[rr][j], 2, 64);
        }
    float mx[4];
#pragma unroll
    for (int rr = 0; rr < 4; ++rr) {
        float v = acc[rr][0] + cb[0];
#pragma unroll
        for (int j = 1; j < PICK; ++j) v = fmaxf(v, acc[rr][j] + cb[j]);
        mx[rr] = v;
    }
    float sel = (s == 0) ? mx[0] : (s == 1) ? mx[1] : (s == 2) ? mx[2] : mx[3];
    pooled[w * 64 + s * 16 + g] = sel;
    __syncthreads();

    // phase B: thread t owns col t*4; re-walk the block's 256 rows (L2/L3-hot)
    const float* tp = emb + bbase * DIM + t * 4;
    float4 o = {0.f, 0.f, 0.f, 0.f};
#pragma unroll 8
    for (int r = 0; r < 256; ++r) {
        float p = pooled[r];
        float4 v = *(const float4*)(tp + (size_t)r * DIM);
        o.x += p * v.x; o.y += p * v.y; o.z += p * v.z; o.w += p * v.w;
    }
    atomicAdd(&out[t * 4 + 0], o.x);
    atomicAdd(&out[t * 4 + 1], o.y);
    atomicAdd(&out[t * 4 + 2], o.z);
    atomicAdd(&out[t * 4 + 3], o.w);
}

// local top-12 of each 1024-chunk of maxv -> 64 blocks x 12 candidates
__global__ void __launch_bounds__(256)
top12_local(const float* __restrict__ maxv, float* __restrict__ cand_v,
            int* __restrict__ cand_i) {
    int t = threadIdx.x;
    int base = blockIdx.x * 1024;
    __shared__ float mv[1024];
    __shared__ float sv[256];
    __shared__ int si[256];
    for (int i = t; i < 1024; i += 256) mv[i] = maxv[base + i];
    __syncthreads();
    for (int k = 0; k < PICK; ++k) {
        float bv = -3e38f; int bi = 0x7fffffff;
        for (int i = t; i < 1024; i += 256) {
            float v = mv[i];
            if (v > bv || (v == bv && base + i < bi)) { bv = v; bi = base + i; }
        }
        sv[t] = bv; si[t] = bi;
        __syncthreads();
        for (int s = 128; s > 0; s >>= 1) {
            if (t < s) {
                if (sv[t + s] > sv[t] || (sv[t + s] == sv[t] && si[t + s] < si[t])) {
                    sv[t] = sv[t + s]; si[t] = si[t + s];
                }
            }
            __syncthreads();
        }
        if (t == 0) {
            cand_v[blockIdx.x * PICK + k] = sv[0];
            cand_i[blockIdx.x * PICK + k] = si[0];
            mv[si[0] - base] = -3e38f;
        }
        __syncthreads();
    }
}

// merge 768 candidates -> global top-12 indices
__global__ void __launch_bounds__(256)
top12_merge(const float* __restrict__ cand_v, const int* __restrict__ cand_i,
            int* __restrict__ top_idx) {
    int t = threadIdx.x;
    __shared__ float mv[768];
    __shared__ int mi[768];
    __shared__ float sv[256];
    __shared__ int si[256];
    __shared__ int sl[256];
    for (int i = t; i < 768; i += 256) { mv[i] = cand_v[i]; mi[i] = cand_i[i]; }
    __syncthreads();
    for (int k = 0; k < PICK; ++k) {
        float bv = -3e38f; int bi = 0x7fffffff; int bl = -1;
        for (int i = t; i < 768; i += 256) {
            float v = mv[i]; int ii = mi[i];
            if (v > bv || (v == bv && ii < bi)) { bv = v; bi = ii; bl = i; }
        }
        sv[t] = bv; si[t] = bi; sl[t] = bl;
        __syncthreads();
        for (int s = 128; s > 0; s >>= 1) {
            if (t < s) {
                if (sv[t + s] > sv[t] || (sv[t + s] == sv[t] && si[t + s] < si[t])) {
                    sv[t] = sv[t + s]; si[t] = si[t + s]; sl[t] = sl[t + s];
                }
            }
            __syncthreads();
        }
        if (t == 0) { top_idx[k] = si[0]; mv[sl[0]] = -3e38f; }
        __syncthreads();
    }
}

extern "C" void kernel_launch(void* const* d_in, const int* in_sizes, int n_in,
                              void* d_out, int out_size, void* d_ws, size_t ws_size,
                              hipStream_t stream) {
    const float* emb = (const float*)d_in[0];
    const float* Wq  = (const float*)d_in[1];
    const float* bq  = (const float*)d_in[2];
    const float* Wk  = (const float*)d_in[3];
    const float* bk  = (const float*)d_in[4];
    const int* indices = (const int*)d_in[5];
    float* out = (float*)d_out;
    float* ws = (float*)d_ws;

    float* NK      = ws;             // 12288
    float* Qr      = ws + 12288;     // 12288
    float* M       = ws + 24576;     // 12288 (zeroed)
    float* Rt      = ws + 36864;     // 12288 (zeroed)
    float* c0      = ws + 49152;     // 16    (zeroed)
    float* c1      = ws + 49168;     // 16    (zeroed)
    float* cand_v  = ws + 49184;     // 768
    int*   cand_i  = (int*)(ws + 49952);   // 768
    int*   top_idx = (int*)(ws + 50720);   // 16
    float* maxv    = ws + 50736;     // 65536

    hipMemsetAsync(M, 0, (size_t)(12288 * 2 + 32) * sizeof(float), stream);
    hipMemsetAsync(out, 0, DIM * sizeof(float), stream);

    rows12_kernel<<<1024, 256, 0, stream>>>(emb, Wk, bk, indices, NK);
    colmat_kernel<<<129, 256, 0, stream>>>(Wq, NK, bq, M, c0);
    pass1_kernel<<<256, 256, 0, stream>>>(emb, M, c0, maxv);
    top12_local<<<64, 256, 0, stream>>>(maxv, cand_v, cand_i);
    top12_merge<<<1, 256, 0, stream>>>(cand_v, cand_i, top_idx);
    rows12_kernel<<<1024, 256, 0, stream>>>(emb, Wq, bq, top_idx, Qr);
    colmat_kernel<<<129, 256, 0, stream>>>(Wk, Qr, bk, Rt, c1);
    pass2_kernel<<<256, 256, 0, stream>>>(emb, Rt, c1, out);
}